// Round 8
// baseline (107.218 us; speedup 1.0000x reference)
//
#include <hip/hip_runtime.h>

// out[b,m,d,f] = sum_{a,c} x[b,m,a,f] * y[b,m,c,f] * cgc[a,d,c]
// Round 13 (resubmit; R7 slot was an infra failure): R6 structure at R6
// parallelism + counted-vmcnt barriers.
//
// R12 post-mortem: counted-vmcnt itself verified correct, but BM=8 cut the
// grid to 512 blocks = 2/CU (Occupancy 19%) -> 2x regression from starved
// parallelism, lever untested. This round is the clean A/B vs R6:
//   - BM_PER_BLOCK=4, NBUF=2 (32KB LDS), 1024 blocks x 256 thr = 4 blocks/CU
//   - per iter: s_waitcnt vmcnt(N) -> s_barrier -> STAGE(i+1) -> COMPUTE(i)
//     N = 0,8,8,8: retires only G(i) (a full iteration old); the 8 stores of
//     iter i-1 stay in flight across the barrier (R6 drained vmcnt(0) here).
//   - STAGE after barrier: buf (i+1)&1 was last read in compute(i-1); every
//     wave passed this barrier only after its compute(i-1), and all its LDS
//     reads retired before its stores issued -> overwrite is safe.
//   - no sched_barrier pinning (m141); asm "memory" clobber orders the
//     compiler's own LDS reads / stores / gload_lds around the waits.
//
// Verified MFMA mapping (R3-R12): A elem j = cgc[2t+qh][L][c0+j],
// B elem j = x[2t+qh][f]*y[c0+j][f], D row=quad*4+r col=L.

typedef __attribute__((ext_vector_type(2))) _Float16 half2v;
typedef __attribute__((ext_vector_type(8))) _Float16 half8;
typedef __attribute__((ext_vector_type(4))) float    floatx4;

#define AA 16
#define FF 128
#define BM_PER_BLOCK 4

union H8 { half2v h2[4]; half8 h8; };

static __device__ __forceinline__ half2v pkrtz(float a, float b) {
    return __builtin_bit_cast(half2v, __builtin_amdgcn_cvt_pkrtz(a, b));
}

static __device__ __forceinline__ void gload_lds16(const float* g, float* l) {
    __builtin_amdgcn_global_load_lds(
        (const __attribute__((address_space(1))) void*)g,
        (__attribute__((address_space(3))) void*)l,
        16, 0, 0);
}

#define WAITB(N) do {                                            \
    asm volatile("s_waitcnt vmcnt(" #N ")" ::: "memory");        \
    __builtin_amdgcn_s_barrier();                                \
} while (0)

__global__ __launch_bounds__(256, 4)
void tpc_mfma_cnt_kernel(const float* __restrict__ x,
                         const float* __restrict__ y,
                         const float* __restrict__ cgc,
                         float* __restrict__ out) {
    __shared__ float lx[2][AA * FF];   // 2 x 8KB
    __shared__ float ly[2][AA * FF];   // 2 x 8KB

    const int tid  = threadIdx.x;
    const int w    = tid >> 6;         // wave 0..3
    const int lane = tid & 63;
    const int L    = lane & 15;        // A: m(=d); B: n(=f in tile); D: col
    const int quad = lane >> 4;
    const int qh   = quad >> 1;        // a parity
    const int c0   = (quad & 1) * 8;   // c sub-range

    const int bm0 = blockIdx.x * BM_PER_BLOCK;
    const size_t stride = (size_t)(AA * FF);
    const int off = w * 512 + lane * 4;          // this thread's staging slot
    const int f0  = w * 32 + L;                  // wave w owns f-tiles 2w,2w+1

    auto STAGE = [&](int i) {
        const float* xb = x + (size_t)(bm0 + i) * stride;
        const float* yb = y + (size_t)(bm0 + i) * stride;
        float* lxd = &lx[i & 1][0];
        float* lyd = &ly[i & 1][0];
        gload_lds16(xb + off,       lxd + off);
        gload_lds16(xb + off + 256, lxd + off + 256);
        gload_lds16(yb + off,       lyd + off);
        gload_lds16(yb + off + 256, lyd + off + 256);
    };

    // ---- prologue: stage bm0; W-frag build overlaps its latency ----
    STAGE(0);

    half8 wfrag[8];
#pragma unroll
    for (int t = 0; t < 8; ++t) {
        const float* wp = cgc + (2 * t + qh) * (AA * AA) + L * AA + c0;
        const floatx4 w0 = *(const floatx4*)(wp);
        const floatx4 w1 = *(const floatx4*)(wp + 4);
        H8 wa;
        wa.h2[0] = pkrtz(w0.x, w0.y);
        wa.h2[1] = pkrtz(w0.z, w0.w);
        wa.h2[2] = pkrtz(w1.x, w1.y);
        wa.h2[3] = pkrtz(w1.z, w1.w);
        wfrag[t] = wa.h8;
    }

    auto COMPUTE = [&](int i) {
        const float* lxc = &lx[i & 1][0];
        const float* lyc = &ly[i & 1][0];

        float xvA[8], xvB[8], yvA[8], yvB[8];
#pragma unroll
        for (int j = 0; j < 8; ++j) {
            yvA[j] = lyc[(c0 + j) * FF + f0];
            yvB[j] = lyc[(c0 + j) * FF + f0 + 16];
        }
#pragma unroll
        for (int t = 0; t < 8; ++t) {
            xvA[t] = lxc[(2 * t + qh) * FF + f0];
            xvB[t] = lxc[(2 * t + qh) * FF + f0 + 16];
        }

        half2v ypA[4], ypB[4];
#pragma unroll
        for (int jj = 0; jj < 4; ++jj) {
            ypA[jj] = pkrtz(yvA[2 * jj], yvA[2 * jj + 1]);
            ypB[jj] = pkrtz(yvB[2 * jj], yvB[2 * jj + 1]);
        }

        floatx4 acc0 = {0.f, 0.f, 0.f, 0.f};
        floatx4 acc1 = {0.f, 0.f, 0.f, 0.f};
#pragma unroll
        for (int t = 0; t < 8; ++t) {
            half2v xp = pkrtz(xvA[t], xvA[t]);
            H8 b0;
            b0.h2[0] = xp * ypA[0];
            b0.h2[1] = xp * ypA[1];
            b0.h2[2] = xp * ypA[2];
            b0.h2[3] = xp * ypA[3];
            acc0 = __builtin_amdgcn_mfma_f32_16x16x32_f16(wfrag[t], b0.h8, acc0, 0, 0, 0);

            xp = pkrtz(xvB[t], xvB[t]);
            H8 b1;
            b1.h2[0] = xp * ypB[0];
            b1.h2[1] = xp * ypB[1];
            b1.h2[2] = xp * ypB[2];
            b1.h2[3] = xp * ypB[3];
            acc1 = __builtin_amdgcn_mfma_f32_16x16x32_f16(wfrag[t], b1.h8, acc1, 0, 0, 0);
        }

        float* ob = out + (size_t)(bm0 + i) * stride;
#pragma unroll
        for (int r = 0; r < 4; ++r) {
            const int row = (quad * 4 + r) * FF;
            ob[row + f0]      = acc0[r];
            ob[row + f0 + 16] = acc1[r];
        }
    };

    // ---- main loop: WAIT(counted) -> barrier -> stage next -> compute ----
    // per-wave VMEM/iter: 4 gload_lds (G) + 8 stores (S).
    // queue at WAIT(i): [G(i)4, S(i-1)8] -> N=0 (only G(0) outstanding), then 8.
    WAITB(0); STAGE(1); COMPUTE(0);
    WAITB(8); STAGE(2); COMPUTE(1);
    WAITB(8); STAGE(3); COMPUTE(2);
    WAITB(8);           COMPUTE(3);
}

extern "C" void kernel_launch(void* const* d_in, const int* in_sizes, int n_in,
                              void* d_out, int out_size, void* d_ws, size_t ws_size,
                              hipStream_t stream) {
    const float* x   = (const float*)d_in[0];
    const float* y   = (const float*)d_in[1];
    const float* cgc = (const float*)d_in[2];
    float* out = (float*)d_out;

    // 4096 bm / 4 per block = 1024 blocks x 256 threads (4 blocks/CU, 32KB LDS)
    hipLaunchKernelGGL(tpc_mfma_cnt_kernel, dim3(1024), dim3(256), 0, stream,
                       x, y, cgc, out);
}